// Round 1
// baseline (44.921 us; speedup 1.0000x reference)
//
#include <hip/hip_runtime.h>

#define N_ANCHORS 100000
#define BATCH 4
#define N_GT 64

__global__ __launch_bounds__(256) void max_iou_kernel(
    const float* __restrict__ anchors,
    const float* __restrict__ gt,
    float* __restrict__ out)
{
    // Stage all gt boxes (4 batches x 64 boxes x 4 coords = 4 KB) + areas in LDS.
    __shared__ float4 s_gt[BATCH * N_GT];
    __shared__ float  s_gt_area[BATCH * N_GT];

    const int tid = threadIdx.x;
    if (tid < BATCH * N_GT) {
        float4 g = reinterpret_cast<const float4*>(gt)[tid];
        s_gt[tid] = g;
        s_gt_area[tid] = (g.z - g.x) * (g.w - g.y);
    }
    __syncthreads();

    const int i = blockIdx.x * blockDim.x + tid;
    if (i >= N_ANCHORS) return;

    const float4 a = reinterpret_cast<const float4*>(anchors)[i];
    const float a_area = (a.z - a.x) * (a.w - a.y);

    #pragma unroll
    for (int b = 0; b < BATCH; ++b) {
        float m = 0.0f;  // IoU is always >= 0, so 0 is a safe identity for max
        #pragma unroll 8
        for (int g = 0; g < N_GT; ++g) {
            const int gi = b * N_GT + g;
            const float4 gb = s_gt[gi];        // wave-uniform -> LDS broadcast
            const float ix1 = fmaxf(a.x, gb.x);
            const float iy1 = fmaxf(a.y, gb.y);
            const float ix2 = fminf(a.z, gb.z);
            const float iy2 = fminf(a.w, gb.w);
            const float iw = fmaxf(ix2 - ix1, 0.0f);
            const float ih = fmaxf(iy2 - iy1, 0.0f);
            const float inter = iw * ih;
            const float uni = a_area + s_gt_area[gi] - inter;
            const float iou = (inter > 0.0f) ? (inter / uni) : 0.0f;
            m = fmaxf(m, iou);
        }
        out[b * N_ANCHORS + i] = m;
    }
}

extern "C" void kernel_launch(void* const* d_in, const int* in_sizes, int n_in,
                              void* d_out, int out_size, void* d_ws, size_t ws_size,
                              hipStream_t stream) {
    const float* anchors = (const float*)d_in[0];  // (100000, 4) fp32
    const float* gt      = (const float*)d_in[1];  // (4, 64, 4) fp32
    float* out           = (float*)d_out;          // (4, 100000) fp32

    const int blocks = (N_ANCHORS + 255) / 256;
    max_iou_kernel<<<blocks, 256, 0, stream>>>(anchors, gt, out);
}

// Round 2
// 21.366 us; speedup vs baseline: 2.1024x; 2.1024x over previous
//
#include <hip/hip_runtime.h>

#define N_ANCHORS 100000
#define BATCH 4
#define N_GT 64

__global__ __launch_bounds__(256) void max_iou_kernel(
    const float4* __restrict__ anchors,
    const float4* __restrict__ gt,
    float* __restrict__ out)
{
    const int i = blockIdx.x * blockDim.x + threadIdx.x;
    const int b = blockIdx.y;
    if (i >= N_ANCHORS) return;

    const float4 a = anchors[i];
    const float a_area = (a.z - a.x) * (a.w - a.y);

    // Running max IoU kept as a fraction num/den to avoid per-iteration divides.
    // 4 independent accumulators break the compare-select dependency chain.
    float num[4] = {0.0f, 0.0f, 0.0f, 0.0f};
    float den[4] = {1.0f, 1.0f, 1.0f, 1.0f};

    const float4* gtb = gt + b * N_GT;

    #pragma unroll 4
    for (int g = 0; g < N_GT; g += 4) {
        #pragma unroll
        for (int k = 0; k < 4; ++k) {
            const float4 gb = gtb[g + k];      // wave-uniform -> scalar/broadcast load
            const float ix1 = fmaxf(a.x, gb.x);
            const float iy1 = fmaxf(a.y, gb.y);
            const float ix2 = fminf(a.z, gb.z);
            const float iy2 = fminf(a.w, gb.w);
            const float iw = fmaxf(ix2 - ix1, 0.0f);
            const float ih = fmaxf(iy2 - iy1, 0.0f);
            const float inter = iw * ih;
            const float g_area = (gb.z - gb.x) * (gb.w - gb.y);
            const float uni = a_area + g_area - inter;
            // inter/uni > num/den  <=>  inter*den > num*uni   (uni, den > 0)
            // inter == 0 candidates can never win (num >= 0), matching the
            // reference's where(inter > 0, inter/union, 0).
            const bool take = inter * den[k] > num[k] * uni;
            num[k] = take ? inter : num[k];
            den[k] = take ? uni   : den[k];
        }
    }

    // Merge the 4 partial maxima.
    float n = num[0], d = den[0];
    #pragma unroll
    for (int k = 1; k < 4; ++k) {
        const bool take = num[k] * d > n * den[k];
        n = take ? num[k] : n;
        d = take ? den[k] : d;
    }

    out[b * N_ANCHORS + i] = n / d;   // n==0 -> 0/1 = 0
}

extern "C" void kernel_launch(void* const* d_in, const int* in_sizes, int n_in,
                              void* d_out, int out_size, void* d_ws, size_t ws_size,
                              hipStream_t stream) {
    const float4* anchors = (const float4*)d_in[0];  // (100000, 4) fp32
    const float4* gt      = (const float4*)d_in[1];  // (4, 64, 4) fp32
    float* out            = (float*)d_out;           // (4, 100000) fp32

    dim3 grid((N_ANCHORS + 255) / 256, BATCH);
    max_iou_kernel<<<grid, 256, 0, stream>>>(anchors, gt, out);
}